// Round 9
// baseline (142.066 us; speedup 1.0000x reference)
//
#include <hip/hip_runtime.h>

// DotProductAttention reduced form (verified rounds 1-8, absmax 0.0156):
//   Qeff[q] = 0.7*Q[q-1] + Q[q] + 0.7*Q[q+1]  (zero pad at edges)
//   out[q]  = softmax_{k <= max(q-1,0)}( Qeff[q]·K[k]/8 + beta[k] ) @ V
// Round 18: r16 (macros, grid 256, 8 waves, 2/SIMD) = best at ~24us attn;
// r17 (512 thr x 4-wave target) was confounded: demand ~150 VGPR > 128 budget
// -> forced spill ate the occupancy gain (flat). The K-loop is stall-bound
// (~3500 wall-cy per ~400-cy comp), so occupancy is still the axis -- get it
// WITHOUT the 128 cliff: 768-thr blocks = 12 waves = 3 waves/SIMD at 1
// block/CU, budget 512/3 = 170 >= demand ~150 -> no spill. Identical r16 body
// (macros, p-loop pairing (pr,31-pr), full ka+vb ping-pong dbuf), only the
// decomposition changes: waves = kh(2) x par(3) x qh(2), K-loop stride 3
// (dbuf stride 6), 6-way epilogue combine via slab[2][2][64][66] (140KB LDS
// pins 1 block/CU; balance comes from the p-loop: every block = 33 tiles).
// Critical tile comps/wave: 16 -> 11. cvt8 unchanged.

typedef short bf16x8 __attribute__((ext_vector_type(8)));
typedef float f32x4  __attribute__((ext_vector_type(4)));

constexpr int S_ = 2048;
constexpr int D_ = 64;
constexpr float LOG2E = 1.44269504088896341f;
constexpr float KSC = 0.125f * LOG2E;   // 1/sqrt(64), log2 domain

// pack two fp32 -> dword of 2 bf16 (round-half-up), lo in low 16
__device__ __forceinline__ unsigned pk2(float lo, float hi) {
    union { float f; unsigned u; } a, b;
    a.f = lo; b.f = hi;
    return __builtin_amdgcn_perm(b.u + 0x8000u, a.u + 0x8000u, 0x07060302u);
}

// ---- fragment pre-swizzle: F[hd][tile][frag][lane][8] bf16 ----
// frag 0..7  = K A-frags  (kh*4 + mb*2 + hh): lane(n,qd) holds
//              K[key = 64t + 32kh + 8(n>>2) + (n&3) + 4mb][d = 32hh + 8qd .. +8]
// frag 8..15 = V^T A-frags (8 + kh*4 + mb): lane(n,qd) holds
//              V[key = 64t + 32kh + 8qd + j][d = 16mb + n], j = 0..7
__global__ __launch_bounds__(256)
void cvt8(const float* __restrict__ K, const float* __restrict__ V,
          unsigned short* __restrict__ F)
{
    __shared__ float T[64][68];   // V^T fp32: [d][key]

    const int bid = blockIdx.x;            // 512: hd = bid&15 -> XCD bid%8 (matches attn)
    const int hd = bid & 15, tt = bid >> 4;
    const float* Kt = K + ((size_t)hd * S_ + tt * 64) * D_;
    const float* Vt = V + ((size_t)hd * S_ + tt * 64) * D_;
    unsigned short* Ft = F + (size_t)(hd * 32 + tt) * 8192;

    const int t = threadIdx.x;
    const int key = t >> 2, d0 = (t & 3) << 4;

    // ---- V: coalesced read -> transposed LDS ----
    {
        const float* vp = Vt + key * D_ + d0;
        #pragma unroll
        for (int i = 0; i < 4; ++i) {
            float4 v4 = *(const float4*)(vp + 4 * i);
            T[d0 + 4 * i + 0][key] = v4.x;
            T[d0 + 4 * i + 1][key] = v4.y;
            T[d0 + 4 * i + 2][key] = v4.z;
            T[d0 + 4 * i + 3][key] = v4.w;
        }
    }

    // ---- K: coalesced read -> direct frag write ----
    {
        const float* kp = Kt + key * D_ + d0;
        float4 a = *(const float4*)(kp);
        float4 b = *(const float4*)(kp + 4);
        float4 c = *(const float4*)(kp + 8);
        float4 d = *(const float4*)(kp + 12);
        uint4 w0 = make_uint4(pk2(a.x, a.y), pk2(a.z, a.w), pk2(b.x, b.y), pk2(b.z, b.w));
        uint4 w1 = make_uint4(pk2(c.x, c.y), pk2(c.z, c.w), pk2(d.x, d.y), pk2(d.z, d.w));
        const int r5 = key & 31;
        const int kh = key >> 5, mb = (r5 >> 2) & 1;
        const int n = ((r5 >> 3) << 2) | (r5 & 3);       // inverse key->M-row perm
        const int hh = d0 >> 5, qd0 = (d0 >> 3) & 3;
        const int f0 = (kh << 2) | (mb << 1) | hh;
        *(uint4*)(Ft + f0 * 512 + ((qd0 << 4) | n) * 8)       = w0;
        *(uint4*)(Ft + f0 * 512 + (((qd0 + 1) << 4) | n) * 8) = w1;
    }
    __syncthreads();

    // ---- V frag emission: contiguous LDS reads, coalesced 16B writes ----
    #pragma unroll
    for (int s = 0; s < 2; ++s) {
        const int slot = t + s * 256;
        const int fr = slot >> 6, lane = slot & 63;
        const int kh = fr >> 2, mb = fr & 3, n = lane & 15, qd = lane >> 4;
        const float* row = &T[mb * 16 + n][kh * 32 + qd * 8];
        uint4 w = make_uint4(pk2(row[0], row[1]), pk2(row[2], row[3]),
                             pk2(row[4], row[5]), pk2(row[6], row[7]));
        *(uint4*)(Ft + (8 + fr) * 512 + lane * 8) = w;
    }
}

// ---- macro (not lambda!) tile load/compute: plain-local access, no escape ----
#define LD_T(TILE, KA, VB) do {                                              \
    const unsigned short* fp_ = Fh + (size_t)(TILE) * 8192;                  \
    KA[0][0] = *(const bf16x8*)(fp_ + kfo[0][0]);                            \
    KA[0][1] = *(const bf16x8*)(fp_ + kfo[0][1]);                            \
    KA[1][0] = *(const bf16x8*)(fp_ + kfo[1][0]);                            \
    KA[1][1] = *(const bf16x8*)(fp_ + kfo[1][1]);                            \
    VB[0] = *(const bf16x8*)(fp_ + vfo[0]);                                  \
    VB[1] = *(const bf16x8*)(fp_ + vfo[1]);                                  \
    VB[2] = *(const bf16x8*)(fp_ + vfo[2]);                                  \
    VB[3] = *(const bf16x8*)(fp_ + vfo[3]);                                  \
} while (0)

#define COMP_T(TILE, KA, VB) do {                                            \
    const int kb_ = ((TILE) << 6) + kvo;                                     \
    const float4 b0_ = *(const float4*)&bl[kb_];                             \
    const float4 b1_ = *(const float4*)&bl[kb_ + 4];                         \
    const float bt_[8] = {b0_.x, b0_.y, b0_.z, b0_.w,                        \
                          b1_.x, b1_.y, b1_.z, b1_.w};                       \
    const f32x4 zz_ = {0, 0, 0, 0};                                          \
    f32x4 acc_[2][2];                                                        \
    acc_[0][0] = __builtin_amdgcn_mfma_f32_16x16x32_bf16(KA[0][1], qb[0][1], \
        __builtin_amdgcn_mfma_f32_16x16x32_bf16(KA[0][0], qb[0][0], zz_, 0, 0, 0), 0, 0, 0); \
    acc_[0][1] = __builtin_amdgcn_mfma_f32_16x16x32_bf16(KA[0][1], qb[1][1], \
        __builtin_amdgcn_mfma_f32_16x16x32_bf16(KA[0][0], qb[1][0], zz_, 0, 0, 0), 0, 0, 0); \
    acc_[1][0] = __builtin_amdgcn_mfma_f32_16x16x32_bf16(KA[1][1], qb[0][1], \
        __builtin_amdgcn_mfma_f32_16x16x32_bf16(KA[1][0], qb[0][0], zz_, 0, 0, 0), 0, 0, 0); \
    acc_[1][1] = __builtin_amdgcn_mfma_f32_16x16x32_bf16(KA[1][1], qb[1][1], \
        __builtin_amdgcn_mfma_f32_16x16x32_bf16(KA[1][0], qb[1][0], zz_, 0, 0, 0), 0, 0, 0); \
    const bool dm_ = (TILE) == nt - 1;                                       \
    _Pragma("unroll")                                                        \
    for (int ng_ = 0; ng_ < 2; ++ng_) {                                      \
        const int qr_ = qbase + (ng_ << 4) + n_l;                            \
        float pv_[8];                                                        \
        float la_ = 0.0f;                                                    \
        _Pragma("unroll")                                                    \
        for (int jj_ = 0; jj_ < 8; ++jj_) {                                  \
            float sv_ = fmaf(acc_[jj_ >> 2][ng_][jj_ & 3], KSC, bt_[jj_]);   \
            if (dm_) {                                                       \
                const int key_ = kb_ + jj_;                                  \
                if (!((key_ < qr_) || (qr_ == 0 && key_ == 0))) sv_ = -1.0e30f; \
            }                                                                \
            pv_[jj_] = __builtin_amdgcn_exp2f(sv_);                          \
            la_ += pv_[jj_];                                                 \
        }                                                                    \
        l[ng_] += la_;                                                       \
        union { unsigned u[4]; bf16x8 v; } pf_;                              \
        pf_.u[0] = pk2(pv_[0], pv_[1]);                                      \
        pf_.u[1] = pk2(pv_[2], pv_[3]);                                      \
        pf_.u[2] = pk2(pv_[4], pv_[5]);                                      \
        pf_.u[3] = pk2(pv_[6], pv_[7]);                                      \
        o[0][ng_] = __builtin_amdgcn_mfma_f32_16x16x32_bf16(VB[0], pf_.v, o[0][ng_], 0, 0, 0); \
        o[1][ng_] = __builtin_amdgcn_mfma_f32_16x16x32_bf16(VB[1], pf_.v, o[1][ng_], 0, 0, 0); \
        o[2][ng_] = __builtin_amdgcn_mfma_f32_16x16x32_bf16(VB[2], pf_.v, o[2][ng_], 0, 0, 0); \
        o[3][ng_] = __builtin_amdgcn_mfma_f32_16x16x32_bf16(VB[3], pf_.v, o[3][ng_], 0, 0, 0); \
    }                                                                        \
} while (0)

__global__ __launch_bounds__(768, 3)
void attn18(const float* __restrict__ Q, const float* __restrict__ beta,
            const unsigned short* __restrict__ F, float* __restrict__ out)
{
    __shared__ float slab[2][2][64][66];   // [kh][par-1][row][0..63: O, 64: l]
    __shared__ float bl[S_];               // exp-scaled beta (log2 domain)

    const int bid = blockIdx.x;
    const int hd = bid & 15;          // head pinned to XCD bid&7 (2 heads/XCD)
    const int pr = bid >> 4;          // pair index -> q-tiles (pr, 31-pr)

    const float* Qh = Q + (size_t)hd * S_ * D_;
    const unsigned short* Fh = F + (size_t)hd * 32 * 8192;

    const int t = threadIdx.x, lane = t & 63;
    const int wv = t >> 6;                      // 0..11
    const int kh = wv & 1;
    const int rem = wv >> 1;                    // 0..5
    const int par = rem % 3, qh = rem / 3;      // par 0..2: every-3rd k-tile
    const int n_l = lane & 15, qd = lane >> 4;

    // ---- stage beta*log2e in LDS once (broadcast reads thereafter) ----
    #pragma unroll
    for (int i = 0; i < 3; ++i) {
        const int idx = t + i * 768;
        if (idx < S_) bl[idx] = beta[idx] * LOG2E;
    }
    __syncthreads();

    // fragment offsets (ushort) within one tile's 8192-ushort block
    const int lo = lane * 8;
    int kfo[2][2], vfo[4];
    #pragma unroll
    for (int mb = 0; mb < 2; ++mb)
        #pragma unroll
        for (int hh = 0; hh < 2; ++hh)
            kfo[mb][hh] = ((kh << 2) | (mb << 1) | hh) * 512 + lo;
    #pragma unroll
    for (int mb = 0; mb < 4; ++mb)
        vfo[mb] = (8 + (kh << 2) + mb) * 512 + lo;

    const int kvo = (kh << 5) + (qd << 3);   // lane's key offset within a tile

    for (int p = 0; p < 2; ++p) {
        const int j = p ? (31 - pr) : pr;
        const int q0 = j << 6;
        const int nt = j + 1;
        const int qbase = q0 + (qh << 5);

        // ---- Qeff B-fragments from global fp32 Q (two q-rows per lane) ----
        bf16x8 qb[2][2];
        #pragma unroll
        for (int ng = 0; ng < 2; ++ng) {
            const int q = qbase + (ng << 4) + n_l;
            const float wp = (q > 0) ? 0.7f : 0.0f;
            const float wn = (q + 1 < S_) ? 0.7f : 0.0f;
            const float* qc = Qh + (size_t)q * D_;
            const float* qpp = qc - ((q > 0) ? D_ : 0);
            const float* qnn = qc + ((q + 1 < S_) ? D_ : 0);
            #pragma unroll
            for (int hh = 0; hh < 2; ++hh) {
                const int d0 = (hh << 5) + (qd << 3);
                float4 c0 = *(const float4*)(qc + d0),  c1 = *(const float4*)(qc + d0 + 4);
                float4 p0 = *(const float4*)(qpp + d0), p1 = *(const float4*)(qpp + d0 + 4);
                float4 n0 = *(const float4*)(qnn + d0), n1 = *(const float4*)(qnn + d0 + 4);
                float e0 = fmaf(wn, n0.x, fmaf(wp, p0.x, c0.x));
                float e1 = fmaf(wn, n0.y, fmaf(wp, p0.y, c0.y));
                float e2 = fmaf(wn, n0.z, fmaf(wp, p0.z, c0.z));
                float e3 = fmaf(wn, n0.w, fmaf(wp, p0.w, c0.w));
                float e4 = fmaf(wn, n1.x, fmaf(wp, p1.x, c1.x));
                float e5 = fmaf(wn, n1.y, fmaf(wp, p1.y, c1.y));
                float e6 = fmaf(wn, n1.z, fmaf(wp, p1.z, c1.z));
                float e7 = fmaf(wn, n1.w, fmaf(wp, p1.w, c1.w));
                union { unsigned u[4]; bf16x8 v; } qu;
                qu.u[0] = pk2(e0, e1); qu.u[1] = pk2(e2, e3);
                qu.u[2] = pk2(e4, e5); qu.u[3] = pk2(e6, e7);
                qb[ng][hh] = qu.v;
            }
        }

        f32x4 o[4][2];
        float l[2] = {0.0f, 0.0f};
        #pragma unroll
        for (int mb = 0; mb < 4; ++mb)
            #pragma unroll
            for (int ng = 0; ng < 2; ++ng) o[mb][ng] = (f32x4){0, 0, 0, 0};

        // ---- barrier-free K-loop over this wave's par class (stride 3) ----
        bf16x8 kaA[2][2], vbA[4];
        bf16x8 kaB[2][2], vbB[4];
        int it = par;
        if (it < nt) {
            LD_T(it, kaA, vbA);
            if (it + 3 < nt) LD_T(it + 3, kaB, vbB);
            while (it + 6 < nt) {
                COMP_T(it, kaA, vbA);
                LD_T(it + 6, kaA, vbA);
                COMP_T(it + 3, kaB, vbB);
                if (it + 9 < nt) LD_T(it + 9, kaB, vbB);
                it += 6;
            }
            COMP_T(it, kaA, vbA);
            if (it + 3 < nt) COMP_T(it + 3, kaB, vbB);
        }

        // ---- epilogue: quad-reduce l, 6-way (kh x par) combine ----
        #pragma unroll
        for (int ng = 0; ng < 2; ++ng) {
            l[ng] += __shfl_xor(l[ng], 16);
            l[ng] += __shfl_xor(l[ng], 32);
        }
        __syncthreads();   // protects previous pass's final reads
        if (par != 0) {
            const int si = par - 1;
            #pragma unroll
            for (int ng = 0; ng < 2; ++ng) {
                const int row = (qh << 5) + (ng << 4) + n_l;
                #pragma unroll
                for (int mb = 0; mb < 4; ++mb)
                    *(float4*)&slab[kh][si][row][(mb << 4) + (qd << 2)] =
                        make_float4(o[mb][ng][0], o[mb][ng][1], o[mb][ng][2], o[mb][ng][3]);
                if (qd == 0) slab[kh][si][row][64] = l[ng];
            }
        }
        __syncthreads();
        if (par == 0) {
            #pragma unroll
            for (int ng = 0; ng < 2; ++ng) {
                const int row = (qh << 5) + (ng << 4) + n_l;
                #pragma unroll
                for (int mb = 0; mb < 4; ++mb) {
                    #pragma unroll
                    for (int si = 0; si < 2; ++si) {
                        float4 pv4 = *(float4*)&slab[kh][si][row][(mb << 4) + (qd << 2)];
                        o[mb][ng][0] += pv4.x; o[mb][ng][1] += pv4.y;
                        o[mb][ng][2] += pv4.z; o[mb][ng][3] += pv4.w;
                    }
                }
                l[ng] += slab[kh][0][row][64] + slab[kh][1][row][64];
                if (kh == 0) {   // publish kh0 totals (same wave read-then-write, in order)
                    #pragma unroll
                    for (int mb = 0; mb < 4; ++mb)
                        *(float4*)&slab[0][0][row][(mb << 4) + (qd << 2)] =
                            make_float4(o[mb][ng][0], o[mb][ng][1], o[mb][ng][2], o[mb][ng][3]);
                    if (qd == 0) slab[0][0][row][64] = l[ng];
                }
            }
        }
        __syncthreads();
        if (par == 0 && kh == 1) {
            #pragma unroll
            for (int ng = 0; ng < 2; ++ng) {
                const int row = (qh << 5) + (ng << 4) + n_l;
                const float inv = 1.0f / (l[ng] + slab[0][0][row][64]);
                float* op = out + ((size_t)hd * S_ + q0 + row) * D_ + (qd << 2);
                #pragma unroll
                for (int mb = 0; mb < 4; ++mb) {
                    float4 pv4 = *(float4*)&slab[0][0][row][(mb << 4) + (qd << 2)];
                    *(float4*)(op + (mb << 4)) =
                        make_float4((o[mb][ng][0] + pv4.x) * inv, (o[mb][ng][1] + pv4.y) * inv,
                                    (o[mb][ng][2] + pv4.z) * inv, (o[mb][ng][3] + pv4.w) * inv);
                }
            }
        }
    }
}

#undef LD_T
#undef COMP_T

extern "C" void kernel_launch(void* const* d_in, const int* in_sizes, int n_in,
                              void* d_out, int out_size, void* d_ws, size_t ws_size,
                              hipStream_t stream) {
    const float* Q    = (const float*)d_in[0];
    const float* K    = (const float*)d_in[1];
    const float* V    = (const float*)d_in[2];
    const float* beta = (const float*)d_in[3];
    // d_in[4]: causal mask (deterministic triu) — handled analytically in-kernel.
    float* out = (float*)d_out;

    unsigned short* F = (unsigned short*)d_ws;   // 16 hd x 32 t x 16 frag x 512 = 8 MB

    cvt8<<<dim3(512), 256, 0, stream>>>(K, V, F);
    attn18<<<dim3(256), 768, 0, stream>>>(Q, beta, F, out);
}

// Round 10
// 108.038 us; speedup vs baseline: 1.3150x; 1.3150x over previous
//
#include <hip/hip_runtime.h>

// DotProductAttention reduced form (verified rounds 1-8, absmax 0.0156):
//   Qeff[q] = 0.7*Q[q-1] + Q[q] + 0.7*Q[q+1]  (zero pad at edges)
//   out[q]  = softmax_{k <= max(q-1,0)}( Qeff[q]·K[k]/8 + beta[k] ) @ V
// Round 19: allocator verdict is in (r10/r13/r14/r18): it picks a high-occ
// VGPR target (64/84/128) IGNORING launch_bounds/waves_per_eu, and spills the
// register-resident tile pipeline (~150 VGPR demand) -> ~8 scratch reloads
// serialize every comp (~4900cy), MfmaUtil 5%, 20-80MB scratch writes. Fix is
// structural: tile data lives in LDS, not registers. Per block: stage each
// 16KB F-tile into a 2x16KB LDS dbuf (async reg-staging: global loads for t+1
// issued before compute(t), ds_write after; one barrier/tile), frags ds_read
// just-in-time (short-lived). Persistent state ~50 VGPR, peak ~90 -> fits any
// target, no spill. Grid 512 = head x q-tile (odd/even map: co-resident pairs
// sum to 33 tiles), 8 waves = kh(2) x qh(4), each wave 16q x 32k x ALL tiles.
// L2 frag traffic halves (tile fetched once per block). LDS 57KB -> 2
// blocks/CU = 4 waves/SIMD. Epilogue: 1-barrier 2-way kh combine via slab.
// cvt8 and frag layout unchanged; key->M-row perm keeps S^T C == PV B.

typedef short bf16x8 __attribute__((ext_vector_type(8)));
typedef float f32x4  __attribute__((ext_vector_type(4)));

constexpr int S_ = 2048;
constexpr int D_ = 64;
constexpr float LOG2E = 1.44269504088896341f;
constexpr float KSC = 0.125f * LOG2E;   // 1/sqrt(64), log2 domain

// pack two fp32 -> dword of 2 bf16 (round-half-up), lo in low 16
__device__ __forceinline__ unsigned pk2(float lo, float hi) {
    union { float f; unsigned u; } a, b;
    a.f = lo; b.f = hi;
    return __builtin_amdgcn_perm(b.u + 0x8000u, a.u + 0x8000u, 0x07060302u);
}

// ---- fragment pre-swizzle: F[hd][tile][frag][lane][8] bf16 ----
// frag 0..7  = K A-frags  (kh*4 + mb*2 + hh): lane(n,qd) holds
//              K[key = 64t + 32kh + 8(n>>2) + (n&3) + 4mb][d = 32hh + 8qd .. +8]
// frag 8..15 = V^T A-frags (8 + kh*4 + mb): lane(n,qd) holds
//              V[key = 64t + 32kh + 8qd + j][d = 16mb + n], j = 0..7
__global__ __launch_bounds__(256)
void cvt8(const float* __restrict__ K, const float* __restrict__ V,
          unsigned short* __restrict__ F)
{
    __shared__ float T[64][68];   // V^T fp32: [d][key]

    const int bid = blockIdx.x;            // 512: hd = bid&15 -> XCD bid%8 (matches attn)
    const int hd = bid & 15, tt = bid >> 4;
    const float* Kt = K + ((size_t)hd * S_ + tt * 64) * D_;
    const float* Vt = V + ((size_t)hd * S_ + tt * 64) * D_;
    unsigned short* Ft = F + (size_t)(hd * 32 + tt) * 8192;

    const int t = threadIdx.x;
    const int key = t >> 2, d0 = (t & 3) << 4;

    // ---- V: coalesced read -> transposed LDS ----
    {
        const float* vp = Vt + key * D_ + d0;
        #pragma unroll
        for (int i = 0; i < 4; ++i) {
            float4 v4 = *(const float4*)(vp + 4 * i);
            T[d0 + 4 * i + 0][key] = v4.x;
            T[d0 + 4 * i + 1][key] = v4.y;
            T[d0 + 4 * i + 2][key] = v4.z;
            T[d0 + 4 * i + 3][key] = v4.w;
        }
    }

    // ---- K: coalesced read -> direct frag write ----
    {
        const float* kp = Kt + key * D_ + d0;
        float4 a = *(const float4*)(kp);
        float4 b = *(const float4*)(kp + 4);
        float4 c = *(const float4*)(kp + 8);
        float4 d = *(const float4*)(kp + 12);
        uint4 w0 = make_uint4(pk2(a.x, a.y), pk2(a.z, a.w), pk2(b.x, b.y), pk2(b.z, b.w));
        uint4 w1 = make_uint4(pk2(c.x, c.y), pk2(c.z, c.w), pk2(d.x, d.y), pk2(d.z, d.w));
        const int r5 = key & 31;
        const int kh = key >> 5, mb = (r5 >> 2) & 1;
        const int n = ((r5 >> 3) << 2) | (r5 & 3);       // inverse key->M-row perm
        const int hh = d0 >> 5, qd0 = (d0 >> 3) & 3;
        const int f0 = (kh << 2) | (mb << 1) | hh;
        *(uint4*)(Ft + f0 * 512 + ((qd0 << 4) | n) * 8)       = w0;
        *(uint4*)(Ft + f0 * 512 + (((qd0 + 1) << 4) | n) * 8) = w1;
    }
    __syncthreads();

    // ---- V frag emission: contiguous LDS reads, coalesced 16B writes ----
    #pragma unroll
    for (int s = 0; s < 2; ++s) {
        const int slot = t + s * 256;
        const int fr = slot >> 6, lane = slot & 63;
        const int kh = fr >> 2, mb = fr & 3, n = lane & 15, qd = lane >> 4;
        const float* row = &T[mb * 16 + n][kh * 32 + qd * 8];
        uint4 w = make_uint4(pk2(row[0], row[1]), pk2(row[2], row[3]),
                             pk2(row[4], row[5]), pk2(row[6], row[7]));
        *(uint4*)(Ft + (8 + fr) * 512 + lane * 8) = w;
    }
}

__global__ __launch_bounds__(512, 2)
void attn19(const float* __restrict__ Q, const float* __restrict__ beta,
            const unsigned short* __restrict__ F, float* __restrict__ out)
{
    __shared__ __align__(16) unsigned short fbuf[2][8192];  // 32KB tile dbuf
    __shared__ float slab[64][68];   // [row][0..63: O, 64: l] (kh combine)
    __shared__ float bl[S_];         // exp-scaled beta (log2 domain)

    const int bid = blockIdx.x;
    const int hd = bid & 15;            // head pinned to XCD bid&7 (2 heads/XCD)
    const int rest = bid >> 4;          // 0..31
    // odd/even map: co-resident pair (bid, bid+256) gets j1+j2 = 31 (33 tiles)
    const int j = (rest < 16) ? (31 - 2 * rest) : (2 * (rest - 16));

    const int q0 = j << 6;
    const int nt = j + 1;

    const float* Qh = Q + (size_t)hd * S_ * D_;
    const unsigned short* Fh = F + (size_t)hd * 32 * 8192;

    const int t = threadIdx.x, lane = t & 63;
    const int wv = t >> 6;                  // 0..7
    const int kh = wv & 1, qh = wv >> 1;    // kh: key half, qh: 16-row group
    const int n_l = lane & 15, qd = lane >> 4;
    const int qbase = q0 + (qh << 4);

    // ---- stage beta*log2e in LDS (barrier folded into prologue) ----
    #pragma unroll
    for (int i = 0; i < 4; ++i) bl[t + i * 512] = beta[t + i * 512] * LOG2E;

    // fragment offsets (ushort) within one tile's 8192-ushort LDS copy
    const int lo = lane * 8;
    int kfo[2][2], vfo[4];
    #pragma unroll
    for (int mb = 0; mb < 2; ++mb)
        #pragma unroll
        for (int hh = 0; hh < 2; ++hh)
            kfo[mb][hh] = ((kh << 2) | (mb << 1) | hh) * 512 + lo;
    #pragma unroll
    for (int mb = 0; mb < 4; ++mb)
        vfo[mb] = (8 + (kh << 2) + mb) * 512 + lo;

    const int kvo = (kh << 5) + (qd << 3);   // lane's key offset within a tile

    // ---- Qeff B-fragment from global fp32 Q (one q-row per lane) ----
    bf16x8 qb[2];
    {
        const int q = qbase + n_l;
        const float wp = (q > 0) ? 0.7f : 0.0f;
        const float wn = (q + 1 < S_) ? 0.7f : 0.0f;
        const float* qc = Qh + (size_t)q * D_;
        const float* qpp = qc - ((q > 0) ? D_ : 0);
        const float* qnn = qc + ((q + 1 < S_) ? D_ : 0);
        #pragma unroll
        for (int hh = 0; hh < 2; ++hh) {
            const int d0 = (hh << 5) + (qd << 3);
            float4 c0 = *(const float4*)(qc + d0),  c1 = *(const float4*)(qc + d0 + 4);
            float4 p0 = *(const float4*)(qpp + d0), p1 = *(const float4*)(qpp + d0 + 4);
            float4 n0 = *(const float4*)(qnn + d0), n1 = *(const float4*)(qnn + d0 + 4);
            float e0 = fmaf(wn, n0.x, fmaf(wp, p0.x, c0.x));
            float e1 = fmaf(wn, n0.y, fmaf(wp, p0.y, c0.y));
            float e2 = fmaf(wn, n0.z, fmaf(wp, p0.z, c0.z));
            float e3 = fmaf(wn, n0.w, fmaf(wp, p0.w, c0.w));
            float e4 = fmaf(wn, n1.x, fmaf(wp, p1.x, c1.x));
            float e5 = fmaf(wn, n1.y, fmaf(wp, p1.y, c1.y));
            float e6 = fmaf(wn, n1.z, fmaf(wp, p1.z, c1.z));
            float e7 = fmaf(wn, n1.w, fmaf(wp, p1.w, c1.w));
            union { unsigned u[4]; bf16x8 v; } qu;
            qu.u[0] = pk2(e0, e1); qu.u[1] = pk2(e2, e3);
            qu.u[2] = pk2(e4, e5); qu.u[3] = pk2(e6, e7);
            qb[hh] = qu.v;
        }
    }

    f32x4 o[4];
    float l = 0.0f;
    #pragma unroll
    for (int mb = 0; mb < 4; ++mb) o[mb] = (f32x4){0, 0, 0, 0};

    // ---- prologue: stage tile 0 into fbuf[0] ----
    uint4 sA, sB;
    {
        const unsigned short* gs = Fh + t * 16;
        sA = *(const uint4*)gs;
        sB = *(const uint4*)(gs + 8);
        unsigned short* db = &fbuf[0][t * 16];
        *(uint4*)db = sA;
        *(uint4*)(db + 8) = sB;
    }
    __syncthreads();

    // ---- K-loop: 1 barrier/tile, async staging (load early, write late) ----
    for (int tt = 0; tt < nt; ++tt) {
        if (tt + 1 < nt) {   // issue next tile's global loads before compute
            const unsigned short* gs = Fh + (size_t)(tt + 1) * 8192 + t * 16;
            sA = *(const uint4*)gs;
            sB = *(const uint4*)(gs + 8);
        }
        {   // compute tile tt from fbuf[tt&1]
            const unsigned short* fb = fbuf[tt & 1];
            bf16x8 ka00 = *(const bf16x8*)(fb + kfo[0][0]);
            bf16x8 ka01 = *(const bf16x8*)(fb + kfo[0][1]);
            bf16x8 ka10 = *(const bf16x8*)(fb + kfo[1][0]);
            bf16x8 ka11 = *(const bf16x8*)(fb + kfo[1][1]);
            const int kb = (tt << 6) + kvo;
            const float4 b0 = *(const float4*)&bl[kb];
            const float4 b1 = *(const float4*)&bl[kb + 4];
            const float bt[8] = {b0.x, b0.y, b0.z, b0.w, b1.x, b1.y, b1.z, b1.w};
            const f32x4 zz = {0, 0, 0, 0};
            f32x4 acc[2];
            acc[0] = __builtin_amdgcn_mfma_f32_16x16x32_bf16(ka01, qb[1],
                     __builtin_amdgcn_mfma_f32_16x16x32_bf16(ka00, qb[0], zz, 0, 0, 0), 0, 0, 0);
            acc[1] = __builtin_amdgcn_mfma_f32_16x16x32_bf16(ka11, qb[1],
                     __builtin_amdgcn_mfma_f32_16x16x32_bf16(ka10, qb[0], zz, 0, 0, 0), 0, 0, 0);
            const bool dm = (tt == nt - 1);
            const int qr = qbase + n_l;
            float pv[8];
            float la = 0.0f;
            #pragma unroll
            for (int jj = 0; jj < 8; ++jj) {
                float sv = fmaf(acc[jj >> 2][jj & 3], KSC, bt[jj]);
                if (dm) {
                    const int key = kb + jj;
                    if (!((key < qr) || (qr == 0 && key == 0))) sv = -1.0e30f;
                }
                pv[jj] = __builtin_amdgcn_exp2f(sv);
                la += pv[jj];
            }
            l += la;
            union { unsigned u[4]; bf16x8 v; } pf;
            pf.u[0] = pk2(pv[0], pv[1]);
            pf.u[1] = pk2(pv[2], pv[3]);
            pf.u[2] = pk2(pv[4], pv[5]);
            pf.u[3] = pk2(pv[6], pv[7]);
            bf16x8 vb0 = *(const bf16x8*)(fb + vfo[0]);
            bf16x8 vb1 = *(const bf16x8*)(fb + vfo[1]);
            bf16x8 vb2 = *(const bf16x8*)(fb + vfo[2]);
            bf16x8 vb3 = *(const bf16x8*)(fb + vfo[3]);
            o[0] = __builtin_amdgcn_mfma_f32_16x16x32_bf16(vb0, pf.v, o[0], 0, 0, 0);
            o[1] = __builtin_amdgcn_mfma_f32_16x16x32_bf16(vb1, pf.v, o[1], 0, 0, 0);
            o[2] = __builtin_amdgcn_mfma_f32_16x16x32_bf16(vb2, pf.v, o[2], 0, 0, 0);
            o[3] = __builtin_amdgcn_mfma_f32_16x16x32_bf16(vb3, pf.v, o[3], 0, 0, 0);
        }
        if (tt + 1 < nt) {   // write staged tile to the other buffer
            unsigned short* db = &fbuf[(tt + 1) & 1][t * 16];
            *(uint4*)db = sA;
            *(uint4*)(db + 8) = sB;
        }
        __syncthreads();
    }

    // ---- epilogue: quad-reduce l, 1-barrier 2-way kh combine, store ----
    l += __shfl_xor(l, 16);
    l += __shfl_xor(l, 32);
    const int row = (qh << 4) + n_l;
    if (kh == 1) {
        #pragma unroll
        for (int mb = 0; mb < 4; ++mb)
            *(float4*)&slab[row][(mb << 4) + (qd << 2)] =
                make_float4(o[mb][0], o[mb][1], o[mb][2], o[mb][3]);
        if (qd == 0) slab[row][64] = l;
    }
    __syncthreads();
    if (kh == 0) {
        const float inv = 1.0f / (l + slab[row][64]);
        float* op = out + ((size_t)hd * S_ + q0 + row) * D_ + (qd << 2);
        #pragma unroll
        for (int mb = 0; mb < 4; ++mb) {
            float4 pv4 = *(float4*)&slab[row][(mb << 4) + (qd << 2)];
            *(float4*)(op + (mb << 4)) =
                make_float4((o[mb][0] + pv4.x) * inv, (o[mb][1] + pv4.y) * inv,
                            (o[mb][2] + pv4.z) * inv, (o[mb][3] + pv4.w) * inv);
        }
    }
}

extern "C" void kernel_launch(void* const* d_in, const int* in_sizes, int n_in,
                              void* d_out, int out_size, void* d_ws, size_t ws_size,
                              hipStream_t stream) {
    const float* Q    = (const float*)d_in[0];
    const float* K    = (const float*)d_in[1];
    const float* V    = (const float*)d_in[2];
    const float* beta = (const float*)d_in[3];
    // d_in[4]: causal mask (deterministic triu) — handled analytically in-kernel.
    float* out = (float*)d_out;

    unsigned short* F = (unsigned short*)d_ws;   // 16 hd x 32 t x 16 frag x 512 = 8 MB

    cvt8<<<dim3(512), 256, 0, stream>>>(K, V, F);
    attn19<<<dim3(512), 512, 0, stream>>>(Q, beta, F, out);
}